// Round 2
// baseline (6843.856 us; speedup 1.0000x reference)
//
#include <hip/hip_runtime.h>
#include <math.h>

#define Bg 32
#define Ng 2048
#define Kn 20
#define BNn (Bg*Ng)
#define En (BNn*Kn)
#define Hd 64
#define Cd 40
#define CAP 16

// ---------- weight prep: wpq[d][l<64] = W1a-W1b (x_i side), wpq[d][64+l] = W1b (x_j side)
__global__ void prep_w_kernel(const float* __restrict__ w1c, const float* __restrict__ w1d1,
                              const float* __restrict__ w1d2,
                              float* __restrict__ wpq0, float* __restrict__ wpq1,
                              float* __restrict__ wpq2){
  int t = blockIdx.x*256 + threadIdx.x;
  if (t < 3*128){
    int d = t >> 7, l = t & 127;
    wpq0[t] = (l < 64) ? (w1c[d*64 + l] - w1c[(d+3)*64 + l]) : w1c[(d+3)*64 + (l-64)];
  }
  if (t < 64*128){
    int d = t >> 7, l = t & 127;
    wpq1[t] = (l < 64) ? (w1d1[d*64 + l] - w1d1[(d+64)*64 + l]) : w1d1[(d+64)*64 + (l-64)];
    wpq2[t] = (l < 64) ? (w1d2[d*64 + l] - w1d2[(d+64)*64 + l]) : w1d2[(d+64)*64 + (l-64)];
  }
}

__global__ void zero_kernel(int* __restrict__ p){
  p[blockIdx.x*256 + threadIdx.x] = 0;
}

// ---------- X[BN,D] @ wpq[D,128] -> P[BN,64], Q[BN,64]
template<int D>
__global__ __launch_bounds__(128) void gemm_pq_kernel(const float* __restrict__ x,
                               const float* __restrict__ w,
                               float* __restrict__ P, float* __restrict__ Q){
  __shared__ float xs[8*D];
  int l = threadIdx.x;
  int node0 = blockIdx.x*8;
  float wc[D];
  #pragma unroll
  for (int d=0; d<D; d++) wc[d] = w[d*128 + l];
  for (int i=l; i < 8*D; i += 128) xs[i] = x[(size_t)node0*D + i];
  __syncthreads();
  #pragma unroll
  for (int n=0; n<8; n++){
    float s = 0.f;
    #pragma unroll
    for (int d=0; d<D; d++) s = fmaf(xs[n*D+d], wc[d], s);
    int node = node0 + n;
    if (l < 64) P[(size_t)node*64 + l] = s;
    else        Q[(size_t)node*64 + (l-64)] = s;
  }
}

__global__ __launch_bounds__(256) void sq_kernel(const float* __restrict__ x, float* __restrict__ sq){
  int t = blockIdx.x*256 + threadIdx.x;
  int node = t >> 6, l = t & 63;
  float v = x[(size_t)node*64 + l];
  float s = v*v;
  #pragma unroll
  for (int o=32; o; o>>=1) s += __shfl_xor(s, o, 64);
  if (l == 0) sq[node] = s;
}

// ---------- CSR build for static EdgeConv (atomic-free aggregation afterwards)
__global__ void count_kernel(const int* __restrict__ ei, int* __restrict__ deg){
  int e = blockIdx.x*256 + threadIdx.x;
  atomicAdd(&deg[ei[En + e]], 1);
}

__global__ __launch_bounds__(1024) void scan_kernel(const int* __restrict__ deg,
        int* __restrict__ rowptr, int* __restrict__ cursor){
  __shared__ int ps[1024];
  int t = threadIdx.x;
  int base = t*64;
  int s = 0;
  for (int k=0;k<64;k++) s += deg[base+k];
  ps[t] = s; __syncthreads();
  for (int off=1; off<1024; off<<=1){
    int v = (t>=off) ? ps[t-off] : 0;
    __syncthreads();
    ps[t] += v;
    __syncthreads();
  }
  int run = (t>0) ? ps[t-1] : 0;
  for (int k=0;k<64;k++){
    rowptr[base+k] = run; cursor[base+k] = run;
    run += deg[base+k];
  }
  if (t==1023) rowptr[BNn] = run;
}

__global__ void scatter_kernel(const int* __restrict__ ei, int* __restrict__ cursor,
                               int* __restrict__ csrc){
  int e = blockIdx.x*256 + threadIdx.x;
  int s = ei[e], d = ei[En + e];
  int pos = atomicAdd(&cursor[d], 1);
  csrc[pos] = s;
}

// ---------- static EdgeConv over CSR: out = elu(max_k relu(P[i]+Q[src_k]+b1)@W2 + b2), 0 if deg==0
__global__ __launch_bounds__(64) void econv_kernel(const int* __restrict__ rowptr,
        const int* __restrict__ csrc,
        const float* __restrict__ P, const float* __restrict__ Q,
        const float* __restrict__ b1, const float* __restrict__ w2,
        const float* __restrict__ b2, float* __restrict__ xout){
  __shared__ __align__(16) float ts[2][Hd];
  int l = threadIdx.x;
  float w2c[Hd];
  #pragma unroll
  for (int d=0; d<Hd; d++) w2c[d] = w2[d*Hd + l];
  float b1l = b1[l], b2l = b2[l];
  for (int i = blockIdx.x; i < BNn; i += gridDim.x){
    int r0 = rowptr[i], r1 = rowptr[i+1];
    float pv = P[(size_t)i*Hd + l] + b1l;
    float acc = -INFINITY;
    for (int k=r0; k<r1; k++){
      int j = csrc[k];
      float tv = pv + Q[(size_t)j*Hd + l];
      tv = tv > 0.f ? tv : 0.f;
      int pb = k & 1;
      ts[pb][l] = tv;
      __syncthreads();
      float s = 0.f;
      #pragma unroll
      for (int d=0; d<Hd; d+=4){
        float4 t4 = *(const float4*)&ts[pb][d];
        s = fmaf(t4.x, w2c[d+0], s);
        s = fmaf(t4.y, w2c[d+1], s);
        s = fmaf(t4.z, w2c[d+2], s);
        s = fmaf(t4.w, w2c[d+3], s);
      }
      acc = fmaxf(acc, s);
    }
    float o = 0.f;
    if (r1 > r0){ o = acc + b2l; o = o > 0.f ? o : expm1f(o); }
    xout[(size_t)i*Hd + l] = o;
  }
}

// ---------- kNN: lane owns a row; 4-acc dot, depth-2 register prefetch, lazy LDS-buffered top-k
__device__ __forceinline__ void insert_key(long long (&kb)[Kn], long long key){
  #pragma unroll
  for (int p=Kn-1; p>0; p--){
    long long ins = (key < kb[p]) ? key : kb[p];
    kb[p] = (key < kb[p-1]) ? kb[p-1] : ins;
  }
  kb[0] = (key < kb[0]) ? key : kb[0];
}

__device__ __forceinline__ void merge_buf(long long (&kb)[Kn], long long& kb19,
                                          int& cnt, long long* mybuf){
  for (int c=0; c<CAP; c++){
    if (!__any(c < cnt)) break;
    if (c < cnt) insert_key(kb, mybuf[c]);
  }
  cnt = 0; kb19 = kb[Kn-1];
}

__device__ __forceinline__ void knn_step(const float4* __restrict__ xj4,
    const float* __restrict__ sg, const float (&xr)[Hd], float sr,
    float4 (&BUF)[16], float& SV, int jj, int nx,
    long long (&kb)[Kn], long long& kb19, int& cnt, long long* mybuf){
  float d0=0.f,d1=0.f,d2=0.f,d3=0.f;
  #pragma unroll
  for (int t=0;t<16;t++){
    d0 = fmaf(xr[4*t+0], BUF[t].x, d0);
    d1 = fmaf(xr[4*t+1], BUF[t].y, d1);
    d2 = fmaf(xr[4*t+2], BUF[t].z, d2);
    d3 = fmaf(xr[4*t+3], BUF[t].w, d3);
  }
  float dist = sr - 2.f*((d0+d1)+(d2+d3)) + SV;
  long long key = __double_as_longlong((double)dist) | (long long)jj; // low 29 bits free; j<2048
  if (key < kb19){ mybuf[cnt] = key; cnt++; }
  int nc = nx < Ng ? nx : Ng-1;
  #pragma unroll
  for (int t=0;t<16;t++) BUF[t] = xj4[(size_t)nc*16 + t];
  SV = sg[nc];
  if (__any(cnt >= CAP)) merge_buf(kb, kb19, cnt, mybuf);
}

__global__ __launch_bounds__(64,1) void knn_kernel(const float* __restrict__ x,
        const float* __restrict__ sq, int* __restrict__ idx){
  __shared__ long long lbuf[64*CAP];
  int lane = threadIdx.x;
  int g = blockIdx.x >> 5;
  int row = (blockIdx.x & 31)*64 + lane;
  const float* xg = x + (size_t)g*Ng*Hd;
  const float* sg = sq + (size_t)g*Ng;
  const float4* xj4 = (const float4*)xg;
  long long* mybuf = lbuf + lane*CAP;

  float xr[Hd];
  #pragma unroll
  for (int d=0; d<Hd; d+=4){
    float4 v = *(const float4*)(xg + (size_t)row*Hd + d);
    xr[d]=v.x; xr[d+1]=v.y; xr[d+2]=v.z; xr[d+3]=v.w;
  }
  float sr = sg[row];

  long long kb[Kn];
  #pragma unroll
  for (int t=0;t<Kn;t++) kb[t] = 0x7FFFFFFFFFFFFFFFLL;
  long long kb19 = kb[Kn-1];
  int cnt = 0;

  float4 A[16], B4[16], C4[16];
  float sA, sB, sC;
  #pragma unroll
  for (int t=0;t<16;t++){ A[t]=xj4[t]; B4[t]=xj4[16+t]; C4[t]=xj4[32+t]; }
  sA = sg[0]; sB = sg[1]; sC = sg[2];

  for (int j=0; j<Ng-2; j+=3){
    knn_step(xj4, sg, xr, sr, A,  sA, j,   j+3, kb, kb19, cnt, mybuf);
    knn_step(xj4, sg, xr, sr, B4, sB, j+1, j+4, kb, kb19, cnt, mybuf);
    knn_step(xj4, sg, xr, sr, C4, sC, j+2, j+5, kb, kb19, cnt, mybuf);
  }
  // tail rows 2046 (A), 2047 (B4); prefetch target harmless
  knn_step(xj4, sg, xr, sr, A,  sA, Ng-2, 0, kb, kb19, cnt, mybuf);
  knn_step(xj4, sg, xr, sr, B4, sB, Ng-1, 0, kb, kb19, cnt, mybuf);
  merge_buf(kb, kb19, cnt, mybuf);

  int node = g*Ng + row;
  #pragma unroll
  for (int t=0;t<Kn;t++) idx[(size_t)node*Kn + t] = g*Ng + (int)(kb[t] & (long long)(Ng-1));
}

// ---------- dynamic EdgeConv stage 2: out = max_k relu(P[i]+Q[j_k]+b1)@W2 + b2 (opt ELU)
template<bool ELU>
__global__ __launch_bounds__(64) void dedge_kernel(const float* __restrict__ P, const float* __restrict__ Q,
        const int* __restrict__ idx, const float* __restrict__ b1,
        const float* __restrict__ w2, const float* __restrict__ b2,
        float* __restrict__ out){
  __shared__ __align__(16) float ts[2][Hd];
  int l = threadIdx.x;
  float w2c[Hd];
  #pragma unroll
  for (int d=0; d<Hd; d++) w2c[d] = w2[d*Hd + l];
  float b1l = b1[l], b2l = b2[l];
  for (int i = blockIdx.x; i < BNn; i += gridDim.x){
    float pv = P[(size_t)i*Hd + l] + b1l;
    float acc = -INFINITY;
    for (int k=0; k<Kn; k++){
      int j = idx[(size_t)i*Kn + k];
      float t = pv + Q[(size_t)j*Hd + l];
      t = t > 0.f ? t : 0.f;
      int pb = k & 1;
      ts[pb][l] = t;
      __syncthreads();
      float s = 0.f;
      #pragma unroll
      for (int d=0; d<Hd; d+=4){
        float4 tv = *(const float4*)&ts[pb][d];
        s = fmaf(tv.x, w2c[d+0], s);
        s = fmaf(tv.y, w2c[d+1], s);
        s = fmaf(tv.z, w2c[d+2], s);
        s = fmaf(tv.w, w2c[d+3], s);
      }
      acc = fmaxf(acc, s);
    }
    float o = acc + b2l;
    if (ELU) o = o > 0.f ? o : expm1f(o);
    out[(size_t)i*Hd + l] = o;
  }
}

__global__ __launch_bounds__(64) void final_kernel(const float* __restrict__ h,
        const float* __restrict__ w, const float* __restrict__ bias,
        float* __restrict__ out){
  __shared__ float xs[Hd];
  int c = threadIdx.x;
  float wc[Hd];
  float bc = 0.f;
  if (c < Cd){
    #pragma unroll
    for (int d=0; d<Hd; d++) wc[d] = w[d*Cd + c];
    bc = bias[c];
  }
  for (int i = blockIdx.x; i < BNn; i += gridDim.x){
    __syncthreads();
    xs[c] = h[(size_t)i*Hd + c];
    __syncthreads();
    if (c < Cd){
      float s = bc;
      #pragma unroll
      for (int d=0; d<Hd; d++) s = fmaf(xs[d], wc[d], s);
      out[(size_t)i*Cd + c] = s;
    }
  }
}

extern "C" void kernel_launch(void* const* d_in, const int* in_sizes, int n_in,
                              void* d_out, int out_size, void* d_ws, size_t ws_size,
                              hipStream_t stream){
  const float* x0   = (const float*)d_in[0];
  const int*   ei   = (const int*)d_in[1];
  const float* c1w1 = (const float*)d_in[3];
  const float* c1b1 = (const float*)d_in[4];
  const float* c1w2 = (const float*)d_in[5];
  const float* c1b2 = (const float*)d_in[6];
  const float* d1w1 = (const float*)d_in[7];
  const float* d1b1 = (const float*)d_in[8];
  const float* d1w2 = (const float*)d_in[9];
  const float* d1b2 = (const float*)d_in[10];
  const float* d2w1 = (const float*)d_in[11];
  const float* d2b1 = (const float*)d_in[12];
  const float* d2w2 = (const float*)d_in[13];
  const float* d2b2 = (const float*)d_in[14];
  const float* linw = (const float*)d_in[15];
  const float* linb = (const float*)d_in[16];
  float* out = (float*)d_out;

  char* ws = (char*)d_ws;
  size_t off = 0;
  auto alloc = [&](size_t bytes)->char*{
    char* p = ws + off; off += (bytes + 255) & ~(size_t)255; return p;
  };
  float* X    = (float*)alloc(sizeof(float)*(size_t)BNn*Hd);
  float* P    = (float*)alloc(sizeof(float)*(size_t)BNn*Hd);
  float* Q    = (float*)alloc(sizeof(float)*(size_t)BNn*Hd);
  float* H2   = (float*)alloc(sizeof(float)*(size_t)BNn*Hd);
  int*   SHRD = (int*)alloc(sizeof(int)*(size_t)En);        // CSRC, later IDX
  int*   DEG  = (int*)alloc(sizeof(int)*BNn);
  int*   RPTR = (int*)alloc(sizeof(int)*(BNn+1));
  int*   CUR  = (int*)alloc(sizeof(int)*BNn);
  float* SQ   = (float*)alloc(sizeof(float)*BNn);
  float* WPQ0 = (float*)alloc(sizeof(float)*3*128);
  float* WPQ1 = (float*)alloc(sizeof(float)*64*128);
  float* WPQ2 = (float*)alloc(sizeof(float)*64*128);
  int*   CSRC = SHRD;
  int*   IDX  = SHRD;
  (void)ws_size; (void)in_sizes; (void)n_in; (void)out_size;

  // static EdgeConv via CSR (no 84M-atomic segment-max)
  prep_w_kernel<<<32, 256, 0, stream>>>(c1w1, d1w1, d2w1, WPQ0, WPQ1, WPQ2);
  zero_kernel<<<BNn/256, 256, 0, stream>>>(DEG);
  count_kernel<<<En/256, 256, 0, stream>>>(ei, DEG);
  gemm_pq_kernel<3><<<BNn/8, 128, 0, stream>>>(x0, WPQ0, P, Q);
  scan_kernel<<<1, 1024, 0, stream>>>(DEG, RPTR, CUR);
  scatter_kernel<<<En/256, 256, 0, stream>>>(ei, CUR, CSRC);
  econv_kernel<<<8192, 64, 0, stream>>>(RPTR, CSRC, P, Q, c1b1, c1w2, c1b2, X);

  // dynamic layer 1
  sq_kernel<<<BNn*Hd/256, 256, 0, stream>>>(X, SQ);
  gemm_pq_kernel<64><<<BNn/8, 128, 0, stream>>>(X, WPQ1, P, Q);
  knn_kernel<<<Bg*32, 64, 0, stream>>>(X, SQ, IDX);
  dedge_kernel<true><<<8192, 64, 0, stream>>>(P, Q, IDX, d1b1, d1w2, d1b2, X);

  // dynamic layer 2
  sq_kernel<<<BNn*Hd/256, 256, 0, stream>>>(X, SQ);
  gemm_pq_kernel<64><<<BNn/8, 128, 0, stream>>>(X, WPQ2, P, Q);
  knn_kernel<<<Bg*32, 64, 0, stream>>>(X, SQ, IDX);
  dedge_kernel<false><<<8192, 64, 0, stream>>>(P, Q, IDX, d2b1, d2w2, d2b2, H2);

  final_kernel<<<8192, 64, 0, stream>>>(H2, linw, linb, out);
}

// Round 3
// 3417.688 us; speedup vs baseline: 2.0025x; 2.0025x over previous
//
#include <hip/hip_runtime.h>
#include <math.h>

#define Bg 32
#define Ng 2048
#define Kn 20
#define BNn (Bg*Ng)
#define En (BNn*Kn)
#define Hd 64
#define Cd 40
#define CAP 8

// ---------- weight prep: wpq[d][l<64] = W1a-W1b (x_i side), wpq[d][64+l] = W1b (x_j side)
__global__ void prep_w_kernel(const float* __restrict__ w1c, const float* __restrict__ w1d1,
                              const float* __restrict__ w1d2,
                              float* __restrict__ wpq0, float* __restrict__ wpq1,
                              float* __restrict__ wpq2){
  int t = blockIdx.x*256 + threadIdx.x;
  if (t < 3*128){
    int d = t >> 7, l = t & 127;
    wpq0[t] = (l < 64) ? (w1c[d*64 + l] - w1c[(d+3)*64 + l]) : w1c[(d+3)*64 + (l-64)];
  }
  if (t < 64*128){
    int d = t >> 7, l = t & 127;
    wpq1[t] = (l < 64) ? (w1d1[d*64 + l] - w1d1[(d+64)*64 + l]) : w1d1[(d+64)*64 + (l-64)];
    wpq2[t] = (l < 64) ? (w1d2[d*64 + l] - w1d2[(d+64)*64 + l]) : w1d2[(d+64)*64 + (l-64)];
  }
}

__global__ void zero_kernel(int* __restrict__ p){
  p[blockIdx.x*256 + threadIdx.x] = 0;
}

// ---------- X[BN,D] @ wpq[D,128] -> P[BN,64], Q[BN,64]
template<int D>
__global__ __launch_bounds__(128) void gemm_pq_kernel(const float* __restrict__ x,
                               const float* __restrict__ w,
                               float* __restrict__ P, float* __restrict__ Q){
  __shared__ float xs[8*D];
  int l = threadIdx.x;
  int node0 = blockIdx.x*8;
  float wc[D];
  #pragma unroll
  for (int d=0; d<D; d++) wc[d] = w[d*128 + l];
  for (int i=l; i < 8*D; i += 128) xs[i] = x[(size_t)node0*D + i];
  __syncthreads();
  #pragma unroll
  for (int n=0; n<8; n++){
    float s = 0.f;
    #pragma unroll
    for (int d=0; d<D; d++) s = fmaf(xs[n*D+d], wc[d], s);
    int node = node0 + n;
    if (l < 64) P[(size_t)node*64 + l] = s;
    else        Q[(size_t)node*64 + (l-64)] = s;
  }
}

__global__ __launch_bounds__(256) void sq_kernel(const float* __restrict__ x, float* __restrict__ sq){
  int t = blockIdx.x*256 + threadIdx.x;
  int node = t >> 6, l = t & 63;
  float v = x[(size_t)node*64 + l];
  float s = v*v;
  #pragma unroll
  for (int o=32; o; o>>=1) s += __shfl_xor(s, o, 64);
  if (l == 0) sq[node] = s;
}

// ---------- CSR build for static EdgeConv
__global__ void count_kernel(const int* __restrict__ ei, int* __restrict__ deg){
  int e = blockIdx.x*256 + threadIdx.x;
  atomicAdd(&deg[ei[En + e]], 1);
}

__global__ __launch_bounds__(1024) void scan_kernel(const int* __restrict__ deg,
        int* __restrict__ rowptr, int* __restrict__ cursor){
  __shared__ int ps[1024];
  int t = threadIdx.x;
  int base = t*64;
  int s = 0;
  for (int k=0;k<64;k++) s += deg[base+k];
  ps[t] = s; __syncthreads();
  for (int off=1; off<1024; off<<=1){
    int v = (t>=off) ? ps[t-off] : 0;
    __syncthreads();
    ps[t] += v;
    __syncthreads();
  }
  int run = (t>0) ? ps[t-1] : 0;
  for (int k=0;k<64;k++){
    rowptr[base+k] = run; cursor[base+k] = run;
    run += deg[base+k];
  }
  if (t==1023) rowptr[BNn] = run;
}

__global__ void scatter_kernel(const int* __restrict__ ei, int* __restrict__ cursor,
                               int* __restrict__ csrc){
  int e = blockIdx.x*256 + threadIdx.x;
  int s = ei[e], d = ei[En + e];
  int pos = atomicAdd(&cursor[d], 1);
  csrc[pos] = s;
}

// ---------- static EdgeConv over CSR
__global__ __launch_bounds__(64) void econv_kernel(const int* __restrict__ rowptr,
        const int* __restrict__ csrc,
        const float* __restrict__ P, const float* __restrict__ Q,
        const float* __restrict__ b1, const float* __restrict__ w2,
        const float* __restrict__ b2, float* __restrict__ xout){
  __shared__ __align__(16) float ts[2][Hd];
  int l = threadIdx.x;
  float w2c[Hd];
  #pragma unroll
  for (int d=0; d<Hd; d++) w2c[d] = w2[d*Hd + l];
  float b1l = b1[l], b2l = b2[l];
  for (int i = blockIdx.x; i < BNn; i += gridDim.x){
    int r0 = rowptr[i], r1 = rowptr[i+1];
    float pv = P[(size_t)i*Hd + l] + b1l;
    float acc = -INFINITY;
    for (int k=r0; k<r1; k++){
      int j = csrc[k];
      float tv = pv + Q[(size_t)j*Hd + l];
      tv = tv > 0.f ? tv : 0.f;
      int pb = k & 1;
      ts[pb][l] = tv;
      __syncthreads();
      float s = 0.f;
      #pragma unroll
      for (int d=0; d<Hd; d+=4){
        float4 t4 = *(const float4*)&ts[pb][d];
        s = fmaf(t4.x, w2c[d+0], s);
        s = fmaf(t4.y, w2c[d+1], s);
        s = fmaf(t4.z, w2c[d+2], s);
        s = fmaf(t4.w, w2c[d+3], s);
      }
      acc = fmaxf(acc, s);
    }
    float o = 0.f;
    if (r1 > r0){ o = acc + b2l; o = o > 0.f ? o : expm1f(o); }
    xout[(size_t)i*Hd + l] = o;
  }
}

// ---------- kNN split-K: wave = 16 rows x 4 k-quarters (lane = q*16 + r)
__device__ __forceinline__ void insert_key(long long (&kb)[Kn], long long key){
  #pragma unroll
  for (int p=Kn-1; p>0; p--){
    long long ins = (key < kb[p]) ? key : kb[p];
    kb[p] = (key < kb[p-1]) ? kb[p-1] : ins;
  }
  kb[0] = (key < kb[0]) ? key : kb[0];
}

__device__ __forceinline__ void knn_proc(float4 c0, float4 c1, float4 c2, float4 c3,
    float scur, const float (&xr)[16], float sr, int j,
    long long (&kb)[Kn], long long& kb19, int& cnt, long long* mybuf){
  float d0, d1, d2, d3;
  d0 = xr[ 0]*c0.x; d1 = xr[ 1]*c0.y; d2 = xr[ 2]*c0.z; d3 = xr[ 3]*c0.w;
  d0 = fmaf(xr[ 4], c1.x, d0); d1 = fmaf(xr[ 5], c1.y, d1);
  d2 = fmaf(xr[ 6], c1.z, d2); d3 = fmaf(xr[ 7], c1.w, d3);
  d0 = fmaf(xr[ 8], c2.x, d0); d1 = fmaf(xr[ 9], c2.y, d1);
  d2 = fmaf(xr[10], c2.z, d2); d3 = fmaf(xr[11], c2.w, d3);
  d0 = fmaf(xr[12], c3.x, d0); d1 = fmaf(xr[13], c3.y, d1);
  d2 = fmaf(xr[14], c3.z, d2); d3 = fmaf(xr[15], c3.w, d3);
  float part = (d0 + d1) + (d2 + d3);
  part += __shfl_xor(part, 16, 64);
  part += __shfl_xor(part, 32, 64);          // all lanes: full dot for their row
  float dist = sr - 2.f*part + scur;
  long long key = __double_as_longlong((double)dist) | (long long)j;
  if (key < kb19){ mybuf[(size_t)cnt*64] = key; cnt++; }
  if (__any(cnt >= CAP)){
    #pragma unroll 1
    for (int c=0; c<CAP; c++){
      if (!__any(c < cnt)) break;
      if (c < cnt) insert_key(kb, mybuf[(size_t)c*64]);
    }
    cnt = 0; kb19 = kb[Kn-1];
  }
}

__global__ __launch_bounds__(256,3) void knn_kernel(const float* __restrict__ x,
        const float* __restrict__ sq, int* __restrict__ idx){
  __shared__ long long kbuf[4][CAP][64];   // [wave][slot][lane] -> 2 lanes/bank, conflict-free
  int lane = threadIdx.x & 63;
  int wid  = threadIdx.x >> 6;
  int gw = blockIdx.x*4 + wid;             // 4096 waves, 128 per graph
  int g  = gw >> 7;
  int r  = (gw & 127)*16 + (lane & 15);
  int q  = lane >> 4;
  const float* xg = x + (size_t)g*Ng*Hd;
  const float* sg = sq + (size_t)g*Ng;
  long long* mybuf = &kbuf[wid][0][lane];

  float xr[16];
  {
    const float* pr = xg + (size_t)r*Hd + q*16;
    float4 a = *(const float4*)(pr+0), b = *(const float4*)(pr+4);
    float4 c = *(const float4*)(pr+8), d = *(const float4*)(pr+12);
    xr[0]=a.x; xr[1]=a.y; xr[2]=a.z; xr[3]=a.w;
    xr[4]=b.x; xr[5]=b.y; xr[6]=b.z; xr[7]=b.w;
    xr[8]=c.x; xr[9]=c.y; xr[10]=c.z; xr[11]=c.w;
    xr[12]=d.x; xr[13]=d.y; xr[14]=d.z; xr[15]=d.w;
  }
  float sr = sg[r];

  long long kb[Kn];
  #pragma unroll
  for (int t=0;t<Kn;t++) kb[t] = 0x7FFFFFFFFFFFFFFFLL;
  long long kb19 = 0x7FFFFFFFFFFFFFFFLL;
  int cnt = 0;

  const float* pj = xg + q*16;             // lane's quarter base
  float4 c0,c1,c2,c3, n0,n1,n2,n3;
  float sc, sn;
  c0 = *(const float4*)(pj+0); c1 = *(const float4*)(pj+4);
  c2 = *(const float4*)(pj+8); c3 = *(const float4*)(pj+12);
  sc = sg[0];

  for (int j=0; j<Ng; j+=2){
    {
      const float* p = pj + (size_t)(j+1)*Hd;
      n0 = *(const float4*)(p+0); n1 = *(const float4*)(p+4);
      n2 = *(const float4*)(p+8); n3 = *(const float4*)(p+12);
      sn = sg[j+1];
    }
    knn_proc(c0,c1,c2,c3, sc, xr, sr, j, kb, kb19, cnt, mybuf);
    {
      int j2 = (j+2 < Ng) ? (j+2) : 0;
      const float* p = pj + (size_t)j2*Hd;
      c0 = *(const float4*)(p+0); c1 = *(const float4*)(p+4);
      c2 = *(const float4*)(p+8); c3 = *(const float4*)(p+12);
      sc = sg[j2];
    }
    knn_proc(n0,n1,n2,n3, sn, xr, sr, j+1, kb, kb19, cnt, mybuf);
  }
  // final drain
  #pragma unroll 1
  for (int c=0; c<CAP; c++){
    if (!__any(c < cnt)) break;
    if (c < cnt) insert_key(kb, mybuf[(size_t)c*64]);
  }
  if (q == 0){
    int node = g*Ng + r;
    #pragma unroll
    for (int t=0;t<Kn;t++) idx[(size_t)node*Kn + t] = g*Ng + (int)(kb[t] & (long long)(Ng-1));
  }
}

// ---------- dynamic EdgeConv stage 2
template<bool ELU>
__global__ __launch_bounds__(64) void dedge_kernel(const float* __restrict__ P, const float* __restrict__ Q,
        const int* __restrict__ idx, const float* __restrict__ b1,
        const float* __restrict__ w2, const float* __restrict__ b2,
        float* __restrict__ out){
  __shared__ __align__(16) float ts[2][Hd];
  int l = threadIdx.x;
  float w2c[Hd];
  #pragma unroll
  for (int d=0; d<Hd; d++) w2c[d] = w2[d*Hd + l];
  float b1l = b1[l], b2l = b2[l];
  for (int i = blockIdx.x; i < BNn; i += gridDim.x){
    float pv = P[(size_t)i*Hd + l] + b1l;
    float acc = -INFINITY;
    for (int k=0; k<Kn; k++){
      int j = idx[(size_t)i*Kn + k];
      float t = pv + Q[(size_t)j*Hd + l];
      t = t > 0.f ? t : 0.f;
      int pb = k & 1;
      ts[pb][l] = t;
      __syncthreads();
      float s = 0.f;
      #pragma unroll
      for (int d=0; d<Hd; d+=4){
        float4 tv = *(const float4*)&ts[pb][d];
        s = fmaf(tv.x, w2c[d+0], s);
        s = fmaf(tv.y, w2c[d+1], s);
        s = fmaf(tv.z, w2c[d+2], s);
        s = fmaf(tv.w, w2c[d+3], s);
      }
      acc = fmaxf(acc, s);
    }
    float o = acc + b2l;
    if (ELU) o = o > 0.f ? o : expm1f(o);
    out[(size_t)i*Hd + l] = o;
  }
}

__global__ __launch_bounds__(64) void final_kernel(const float* __restrict__ h,
        const float* __restrict__ w, const float* __restrict__ bias,
        float* __restrict__ out){
  __shared__ float xs[Hd];
  int c = threadIdx.x;
  float wc[Hd];
  float bc = 0.f;
  if (c < Cd){
    #pragma unroll
    for (int d=0; d<Hd; d++) wc[d] = w[d*Cd + c];
    bc = bias[c];
  }
  for (int i = blockIdx.x; i < BNn; i += gridDim.x){
    __syncthreads();
    xs[c] = h[(size_t)i*Hd + c];
    __syncthreads();
    if (c < Cd){
      float s = bc;
      #pragma unroll
      for (int d=0; d<Hd; d++) s = fmaf(xs[d], wc[d], s);
      out[(size_t)i*Cd + c] = s;
    }
  }
}

extern "C" void kernel_launch(void* const* d_in, const int* in_sizes, int n_in,
                              void* d_out, int out_size, void* d_ws, size_t ws_size,
                              hipStream_t stream){
  const float* x0   = (const float*)d_in[0];
  const int*   ei   = (const int*)d_in[1];
  const float* c1w1 = (const float*)d_in[3];
  const float* c1b1 = (const float*)d_in[4];
  const float* c1w2 = (const float*)d_in[5];
  const float* c1b2 = (const float*)d_in[6];
  const float* d1w1 = (const float*)d_in[7];
  const float* d1b1 = (const float*)d_in[8];
  const float* d1w2 = (const float*)d_in[9];
  const float* d1b2 = (const float*)d_in[10];
  const float* d2w1 = (const float*)d_in[11];
  const float* d2b1 = (const float*)d_in[12];
  const float* d2w2 = (const float*)d_in[13];
  const float* d2b2 = (const float*)d_in[14];
  const float* linw = (const float*)d_in[15];
  const float* linb = (const float*)d_in[16];
  float* out = (float*)d_out;

  char* ws = (char*)d_ws;
  size_t off = 0;
  auto alloc = [&](size_t bytes)->char*{
    char* p = ws + off; off += (bytes + 255) & ~(size_t)255; return p;
  };
  float* X    = (float*)alloc(sizeof(float)*(size_t)BNn*Hd);
  float* P    = (float*)alloc(sizeof(float)*(size_t)BNn*Hd);
  float* Q    = (float*)alloc(sizeof(float)*(size_t)BNn*Hd);
  float* H2   = (float*)alloc(sizeof(float)*(size_t)BNn*Hd);
  int*   SHRD = (int*)alloc(sizeof(int)*(size_t)En);        // CSRC, later IDX
  int*   DEG  = (int*)alloc(sizeof(int)*BNn);
  int*   RPTR = (int*)alloc(sizeof(int)*(BNn+1));
  int*   CUR  = (int*)alloc(sizeof(int)*BNn);
  float* SQ   = (float*)alloc(sizeof(float)*BNn);
  float* WPQ0 = (float*)alloc(sizeof(float)*3*128);
  float* WPQ1 = (float*)alloc(sizeof(float)*64*128);
  float* WPQ2 = (float*)alloc(sizeof(float)*64*128);
  int*   CSRC = SHRD;
  int*   IDX  = SHRD;
  (void)ws_size; (void)in_sizes; (void)n_in; (void)out_size;

  prep_w_kernel<<<32, 256, 0, stream>>>(c1w1, d1w1, d2w1, WPQ0, WPQ1, WPQ2);
  zero_kernel<<<BNn/256, 256, 0, stream>>>(DEG);
  count_kernel<<<En/256, 256, 0, stream>>>(ei, DEG);
  gemm_pq_kernel<3><<<BNn/8, 128, 0, stream>>>(x0, WPQ0, P, Q);
  scan_kernel<<<1, 1024, 0, stream>>>(DEG, RPTR, CUR);
  scatter_kernel<<<En/256, 256, 0, stream>>>(ei, CUR, CSRC);
  econv_kernel<<<8192, 64, 0, stream>>>(RPTR, CSRC, P, Q, c1b1, c1w2, c1b2, X);

  // dynamic layer 1
  sq_kernel<<<BNn*Hd/256, 256, 0, stream>>>(X, SQ);
  gemm_pq_kernel<64><<<BNn/8, 128, 0, stream>>>(X, WPQ1, P, Q);
  knn_kernel<<<1024, 256, 0, stream>>>(X, SQ, IDX);
  dedge_kernel<true><<<8192, 64, 0, stream>>>(P, Q, IDX, d1b1, d1w2, d1b2, X);

  // dynamic layer 2
  sq_kernel<<<BNn*Hd/256, 256, 0, stream>>>(X, SQ);
  gemm_pq_kernel<64><<<BNn/8, 128, 0, stream>>>(X, WPQ2, P, Q);
  knn_kernel<<<1024, 256, 0, stream>>>(X, SQ, IDX);
  dedge_kernel<false><<<8192, 64, 0, stream>>>(P, Q, IDX, d2b1, d2w2, d2b2, H2);

  final_kernel<<<8192, 64, 0, stream>>>(H2, linw, linb, out);
}

// Round 4
// 2217.952 us; speedup vs baseline: 3.0857x; 1.5409x over previous
//
#include <hip/hip_runtime.h>
#include <math.h>

#define Bg 32
#define Ng 2048
#define Kn 20
#define BNn (Bg*Ng)
#define En (BNn*Kn)
#define Hd 64
#define Cd 40

// knn tiling
#define RT 128          // rows per block
#define JT 32           // j-tile
#define XRS 132         // Xr LDS stride (mult of 4 for b128 alignment)
#define XJS 36          // Xj LDS stride
#define DSs 33          // D LDS stride (odd -> 2-way max on B reads)
#define CAPk 4

// ---------- weight prep: wpq[d][l<64] = W1a-W1b (x_i side), wpq[d][64+l] = W1b (x_j side)
__global__ void prep_w_kernel(const float* __restrict__ w1c, const float* __restrict__ w1d1,
                              const float* __restrict__ w1d2,
                              float* __restrict__ wpq0, float* __restrict__ wpq1,
                              float* __restrict__ wpq2){
  int t = blockIdx.x*256 + threadIdx.x;
  if (t < 3*128){
    int d = t >> 7, l = t & 127;
    wpq0[t] = (l < 64) ? (w1c[d*64 + l] - w1c[(d+3)*64 + l]) : w1c[(d+3)*64 + (l-64)];
  }
  if (t < 64*128){
    int d = t >> 7, l = t & 127;
    wpq1[t] = (l < 64) ? (w1d1[d*64 + l] - w1d1[(d+64)*64 + l]) : w1d1[(d+64)*64 + (l-64)];
    wpq2[t] = (l < 64) ? (w1d2[d*64 + l] - w1d2[(d+64)*64 + l]) : w1d2[(d+64)*64 + (l-64)];
  }
}

__global__ void zero_kernel(int* __restrict__ p){
  p[blockIdx.x*256 + threadIdx.x] = 0;
}

// ---------- X[BN,D] @ wpq[D,128] -> P[BN,64], Q[BN,64]
template<int D>
__global__ __launch_bounds__(128) void gemm_pq_kernel(const float* __restrict__ x,
                               const float* __restrict__ w,
                               float* __restrict__ P, float* __restrict__ Q){
  __shared__ float xs[8*D];
  int l = threadIdx.x;
  int node0 = blockIdx.x*8;
  float wc[D];
  #pragma unroll
  for (int d=0; d<D; d++) wc[d] = w[d*128 + l];
  for (int i=l; i < 8*D; i += 128) xs[i] = x[(size_t)node0*D + i];
  __syncthreads();
  #pragma unroll
  for (int n=0; n<8; n++){
    float s = 0.f;
    #pragma unroll
    for (int d=0; d<D; d++) s = fmaf(xs[n*D+d], wc[d], s);
    int node = node0 + n;
    if (l < 64) P[(size_t)node*64 + l] = s;
    else        Q[(size_t)node*64 + (l-64)] = s;
  }
}

__global__ __launch_bounds__(256) void sq_kernel(const float* __restrict__ x, float* __restrict__ sq){
  int t = blockIdx.x*256 + threadIdx.x;
  int node = t >> 6, l = t & 63;
  float v = x[(size_t)node*64 + l];
  float s = v*v;
  #pragma unroll
  for (int o=32; o; o>>=1) s += __shfl_xor(s, o, 64);
  if (l == 0) sq[node] = s;
}

// ---------- CSR build for static EdgeConv
__global__ void count_kernel(const int* __restrict__ ei, int* __restrict__ deg){
  int e = blockIdx.x*256 + threadIdx.x;
  atomicAdd(&deg[ei[En + e]], 1);
}

__global__ __launch_bounds__(1024) void scan_kernel(const int* __restrict__ deg,
        int* __restrict__ rowptr, int* __restrict__ cursor){
  __shared__ int ps[1024];
  int t = threadIdx.x;
  int base = t*64;
  int s = 0;
  for (int k=0;k<64;k++) s += deg[base+k];
  ps[t] = s; __syncthreads();
  for (int off=1; off<1024; off<<=1){
    int v = (t>=off) ? ps[t-off] : 0;
    __syncthreads();
    ps[t] += v;
    __syncthreads();
  }
  int run = (t>0) ? ps[t-1] : 0;
  for (int k=0;k<64;k++){
    rowptr[base+k] = run; cursor[base+k] = run;
    run += deg[base+k];
  }
  if (t==1023) rowptr[BNn] = run;
}

__global__ void scatter_kernel(const int* __restrict__ ei, int* __restrict__ cursor,
                               int* __restrict__ csrc){
  int e = blockIdx.x*256 + threadIdx.x;
  int s = ei[e], d = ei[En + e];
  int pos = atomicAdd(&cursor[d], 1);
  csrc[pos] = s;
}

// ---------- static EdgeConv over CSR
__global__ __launch_bounds__(64) void econv_kernel(const int* __restrict__ rowptr,
        const int* __restrict__ csrc,
        const float* __restrict__ P, const float* __restrict__ Q,
        const float* __restrict__ b1, const float* __restrict__ w2,
        const float* __restrict__ b2, float* __restrict__ xout){
  __shared__ __align__(16) float ts[2][Hd];
  int l = threadIdx.x;
  float w2c[Hd];
  #pragma unroll
  for (int d=0; d<Hd; d++) w2c[d] = w2[d*Hd + l];
  float b1l = b1[l], b2l = b2[l];
  for (int i = blockIdx.x; i < BNn; i += gridDim.x){
    int r0 = rowptr[i], r1 = rowptr[i+1];
    float pv = P[(size_t)i*Hd + l] + b1l;
    float acc = -INFINITY;
    for (int k=r0; k<r1; k++){
      int j = csrc[k];
      float tv = pv + Q[(size_t)j*Hd + l];
      tv = tv > 0.f ? tv : 0.f;
      int pb = k & 1;
      ts[pb][l] = tv;
      __syncthreads();
      float s = 0.f;
      #pragma unroll
      for (int d=0; d<Hd; d+=4){
        float4 t4 = *(const float4*)&ts[pb][d];
        s = fmaf(t4.x, w2c[d+0], s);
        s = fmaf(t4.y, w2c[d+1], s);
        s = fmaf(t4.z, w2c[d+2], s);
        s = fmaf(t4.w, w2c[d+3], s);
      }
      acc = fmaxf(acc, s);
    }
    float o = 0.f;
    if (r1 > r0){ o = acc + b2l; o = o > 0.f ? o : expm1f(o); }
    xout[(size_t)i*Hd + l] = o;
  }
}

// ---------- kNN: fused distance-GEMM tile (Phase A) + per-row selection scan (Phase B)
__device__ __forceinline__ void ins20(unsigned long long (&kb)[Kn], unsigned long long key){
  #pragma unroll
  for (int p=Kn-1; p>0; p--){
    unsigned long long ins = (key < kb[p]) ? key : kb[p];
    kb[p] = (key < kb[p-1]) ? kb[p-1] : ins;
  }
  kb[0] = (key < kb[0]) ? key : kb[0];
}

__global__ __launch_bounds__(256,2) void knn_kernel(const float* __restrict__ x,
        const float* __restrict__ sq, int* __restrict__ idx){
  __shared__ __align__(16) float xr[64*XRS];            // [k][r]   33.8 KB
  __shared__ __align__(16) float xj[2][64*XJS];         // [k][j]   18.4 KB
  __shared__ float Dt[RT*DSs];                          // [r][j]   16.9 KB
  __shared__ float sqs[2][JT];
  __shared__ __align__(16) unsigned long long kcand[CAPk][256];  // 8 KB

  int tid = threadIdx.x;
  int g = blockIdx.x >> 4;                // 16 row-groups per graph
  int r0 = (blockIdx.x & 15) * RT;
  const float* xg = x + (size_t)g*Ng*Hd;
  const float* sg = sq + (size_t)g*Ng;

  // stage Xr transposed [k][r] (once)
  #pragma unroll
  for (int rep = 0; rep < 8; rep++){
    int li = rep*1024 + tid*4;
    int r = li >> 6, k = li & 63;
    float4 v = *(const float4*)(xg + (size_t)(r0+r)*Hd + k);
    xr[(k+0)*XRS + r] = v.x; xr[(k+1)*XRS + r] = v.y;
    xr[(k+2)*XRS + r] = v.z; xr[(k+3)*XRS + r] = v.w;
  }
  // stage Xj tile 0
  {
    int jl = tid & 31, kh = tid >> 5;
    const float* p = xg + (size_t)jl*Hd + kh*8;
    float4 a = *(const float4*)p, b = *(const float4*)(p+4);
    int kk = kh*8;
    xj[0][(kk+0)*XJS+jl]=a.x; xj[0][(kk+1)*XJS+jl]=a.y;
    xj[0][(kk+2)*XJS+jl]=a.z; xj[0][(kk+3)*XJS+jl]=a.w;
    xj[0][(kk+4)*XJS+jl]=b.x; xj[0][(kk+5)*XJS+jl]=b.y;
    xj[0][(kk+6)*XJS+jl]=b.z; xj[0][(kk+7)*XJS+jl]=b.w;
    if (tid < JT) sqs[0][tid] = sg[tid];
  }
  int tr = tid >> 3;                      // 0..31 -> rows 4tr..4tr+3
  int tj = tid & 7;                       // 0..7  -> js  4tj..4tj+3
  int lane = tid & 63, w = tid >> 6;
  int rowl = w*32 + (lane & 31);          // 0..127
  int jq = lane >> 5;                     // 0..1

  unsigned long long kb[Kn];
  #pragma unroll
  for (int t=0;t<Kn;t++) kb[t] = ~0ULL;
  unsigned long long kb19 = ~0ULL;
  int cnt = 0;

  __syncthreads();

  for (int t = 0; t < Ng/JT; t++){
    int buf = t & 1;
    // register-prefetch next Xj tile
    float4 pa, pb; float psq = 0.f;
    int tn = t + 1;
    int jl = tid & 31, kh = tid >> 5;
    if (tn < Ng/JT){
      const float* p = xg + (size_t)(tn*JT + jl)*Hd + kh*8;
      pa = *(const float4*)p; pb = *(const float4*)(p+4);
      if (tid < JT) psq = sg[tn*JT + tid];
    }
    // Phase A: 4x4 register-tile GEMM over k=64
    float acc[16];
    #pragma unroll
    for (int i=0;i<16;i++) acc[i] = 0.f;
    #pragma unroll 8
    for (int k=0;k<64;k++){
      float4 a = *(const float4*)&xr[k*XRS + 4*tr];
      float4 b = *(const float4*)&xj[buf][k*XJS + 4*tj];
      acc[ 0] = fmaf(a.x, b.x, acc[ 0]); acc[ 1] = fmaf(a.x, b.y, acc[ 1]);
      acc[ 2] = fmaf(a.x, b.z, acc[ 2]); acc[ 3] = fmaf(a.x, b.w, acc[ 3]);
      acc[ 4] = fmaf(a.y, b.x, acc[ 4]); acc[ 5] = fmaf(a.y, b.y, acc[ 5]);
      acc[ 6] = fmaf(a.y, b.z, acc[ 6]); acc[ 7] = fmaf(a.y, b.w, acc[ 7]);
      acc[ 8] = fmaf(a.z, b.x, acc[ 8]); acc[ 9] = fmaf(a.z, b.y, acc[ 9]);
      acc[10] = fmaf(a.z, b.z, acc[10]); acc[11] = fmaf(a.z, b.w, acc[11]);
      acc[12] = fmaf(a.w, b.x, acc[12]); acc[13] = fmaf(a.w, b.y, acc[13]);
      acc[14] = fmaf(a.w, b.z, acc[14]); acc[15] = fmaf(a.w, b.w, acc[15]);
    }
    __syncthreads();   // prior Phase B done reading Dt
    // epilogue: D[r][j] = sq[j] - 2*dot  (row-constant +sr dropped; order-invariant)
    #pragma unroll
    for (int jj=0;jj<4;jj++){
      float sqv = sqs[buf][4*tj+jj];
      #pragma unroll
      for (int rr=0;rr<4;rr++)
        Dt[(4*tr+rr)*DSs + 4*tj+jj] = fmaf(acc[rr*4+jj], -2.f, sqv);
    }
    // commit prefetched Xj tile
    if (tn < Ng/JT){
      int nb = buf^1, kk = kh*8;
      xj[nb][(kk+0)*XJS+jl]=pa.x; xj[nb][(kk+1)*XJS+jl]=pa.y;
      xj[nb][(kk+2)*XJS+jl]=pa.z; xj[nb][(kk+3)*XJS+jl]=pa.w;
      xj[nb][(kk+4)*XJS+jl]=pb.x; xj[nb][(kk+5)*XJS+jl]=pb.y;
      xj[nb][(kk+6)*XJS+jl]=pb.z; xj[nb][(kk+7)*XJS+jl]=pb.w;
      if (tid < JT) sqs[nb][tid] = psq;
    }
    __syncthreads();   // Dt + next Xj ready
    // Phase B: lane (rowl, jq) scans 16 j's
    int jbase = t*JT;
    #pragma unroll
    for (int i=0;i<16;i++){
      int jloc = jq*16 + i;
      float s = Dt[rowl*DSs + jloc];
      unsigned u = __float_as_uint(s);
      u = ((int)u < 0) ? ~u : (u | 0x80000000u);   // order-preserving fp32->u32
      unsigned long long key = ((unsigned long long)u << 32) | (unsigned)(jbase + jloc);
      if (key < kb19){ kcand[cnt][tid] = key; cnt++; }
      if (__any(cnt >= CAPk)){
        #pragma unroll 1
        for (int c=0;c<CAPk;c++){
          if (!__any(c < cnt)) break;
          unsigned long long kk2 = (c < cnt) ? kcand[c][tid] : ~0ULL;
          ins20(kb, kk2);
        }
        cnt = 0; kb19 = kb[Kn-1];
      }
    }
  }
  // final drain
  #pragma unroll 1
  for (int c=0;c<CAPk;c++){
    if (!__any(c < cnt)) break;
    unsigned long long kk2 = (c < cnt) ? kcand[c][tid] : ~0ULL;
    ins20(kb, kk2);
  }
  // merge jq=1 half into jq=0 via xr region (no longer needed)
  __syncthreads();
  unsigned long long* mg = (unsigned long long*)xr;
  if (jq == 1){
    #pragma unroll
    for (int t=0;t<Kn;t++) mg[rowl*Kn + t] = kb[t];
  }
  __syncthreads();
  if (jq == 0){
    #pragma unroll 1
    for (int t=0;t<Kn;t++) ins20(kb, mg[rowl*Kn + t]);
    int node = g*Ng + r0 + rowl;
    #pragma unroll
    for (int t=0;t<Kn;t++)
      idx[(size_t)node*Kn + t] = g*Ng + (int)(kb[t] & (unsigned long long)(Ng-1));
  }
}

// ---------- dynamic EdgeConv stage 2
template<bool ELU>
__global__ __launch_bounds__(64) void dedge_kernel(const float* __restrict__ P, const float* __restrict__ Q,
        const int* __restrict__ idx, const float* __restrict__ b1,
        const float* __restrict__ w2, const float* __restrict__ b2,
        float* __restrict__ out){
  __shared__ __align__(16) float ts[2][Hd];
  int l = threadIdx.x;
  float w2c[Hd];
  #pragma unroll
  for (int d=0; d<Hd; d++) w2c[d] = w2[d*Hd + l];
  float b1l = b1[l], b2l = b2[l];
  for (int i = blockIdx.x; i < BNn; i += gridDim.x){
    float pv = P[(size_t)i*Hd + l] + b1l;
    float acc = -INFINITY;
    for (int k=0; k<Kn; k++){
      int j = idx[(size_t)i*Kn + k];
      float t = pv + Q[(size_t)j*Hd + l];
      t = t > 0.f ? t : 0.f;
      int pb = k & 1;
      ts[pb][l] = t;
      __syncthreads();
      float s = 0.f;
      #pragma unroll
      for (int d=0; d<Hd; d+=4){
        float4 tv = *(const float4*)&ts[pb][d];
        s = fmaf(tv.x, w2c[d+0], s);
        s = fmaf(tv.y, w2c[d+1], s);
        s = fmaf(tv.z, w2c[d+2], s);
        s = fmaf(tv.w, w2c[d+3], s);
      }
      acc = fmaxf(acc, s);
    }
    float o = acc + b2l;
    if (ELU) o = o > 0.f ? o : expm1f(o);
    out[(size_t)i*Hd + l] = o;
  }
}

__global__ __launch_bounds__(64) void final_kernel(const float* __restrict__ h,
        const float* __restrict__ w, const float* __restrict__ bias,
        float* __restrict__ out){
  __shared__ float xs[Hd];
  int c = threadIdx.x;
  float wc[Hd];
  float bc = 0.f;
  if (c < Cd){
    #pragma unroll
    for (int d=0; d<Hd; d++) wc[d] = w[d*Cd + c];
    bc = bias[c];
  }
  for (int i = blockIdx.x; i < BNn; i += gridDim.x){
    __syncthreads();
    xs[c] = h[(size_t)i*Hd + c];
    __syncthreads();
    if (c < Cd){
      float s = bc;
      #pragma unroll
      for (int d=0; d<Hd; d++) s = fmaf(xs[d], wc[d], s);
      out[(size_t)i*Cd + c] = s;
    }
  }
}

extern "C" void kernel_launch(void* const* d_in, const int* in_sizes, int n_in,
                              void* d_out, int out_size, void* d_ws, size_t ws_size,
                              hipStream_t stream){
  const float* x0   = (const float*)d_in[0];
  const int*   ei   = (const int*)d_in[1];
  const float* c1w1 = (const float*)d_in[3];
  const float* c1b1 = (const float*)d_in[4];
  const float* c1w2 = (const float*)d_in[5];
  const float* c1b2 = (const float*)d_in[6];
  const float* d1w1 = (const float*)d_in[7];
  const float* d1b1 = (const float*)d_in[8];
  const float* d1w2 = (const float*)d_in[9];
  const float* d1b2 = (const float*)d_in[10];
  const float* d2w1 = (const float*)d_in[11];
  const float* d2b1 = (const float*)d_in[12];
  const float* d2w2 = (const float*)d_in[13];
  const float* d2b2 = (const float*)d_in[14];
  const float* linw = (const float*)d_in[15];
  const float* linb = (const float*)d_in[16];
  float* out = (float*)d_out;

  char* ws = (char*)d_ws;
  size_t off = 0;
  auto alloc = [&](size_t bytes)->char*{
    char* p = ws + off; off += (bytes + 255) & ~(size_t)255; return p;
  };
  float* X    = (float*)alloc(sizeof(float)*(size_t)BNn*Hd);
  float* P    = (float*)alloc(sizeof(float)*(size_t)BNn*Hd);
  float* Q    = (float*)alloc(sizeof(float)*(size_t)BNn*Hd);
  float* H2   = (float*)alloc(sizeof(float)*(size_t)BNn*Hd);
  int*   SHRD = (int*)alloc(sizeof(int)*(size_t)En);        // CSRC, later IDX
  int*   DEG  = (int*)alloc(sizeof(int)*BNn);
  int*   RPTR = (int*)alloc(sizeof(int)*(BNn+1));
  int*   CUR  = (int*)alloc(sizeof(int)*BNn);
  float* SQ   = (float*)alloc(sizeof(float)*BNn);
  float* WPQ0 = (float*)alloc(sizeof(float)*3*128);
  float* WPQ1 = (float*)alloc(sizeof(float)*64*128);
  float* WPQ2 = (float*)alloc(sizeof(float)*64*128);
  int*   CSRC = SHRD;
  int*   IDX  = SHRD;
  (void)ws_size; (void)in_sizes; (void)n_in; (void)out_size;

  prep_w_kernel<<<32, 256, 0, stream>>>(c1w1, d1w1, d2w1, WPQ0, WPQ1, WPQ2);
  zero_kernel<<<BNn/256, 256, 0, stream>>>(DEG);
  count_kernel<<<En/256, 256, 0, stream>>>(ei, DEG);
  gemm_pq_kernel<3><<<BNn/8, 128, 0, stream>>>(x0, WPQ0, P, Q);
  scan_kernel<<<1, 1024, 0, stream>>>(DEG, RPTR, CUR);
  scatter_kernel<<<En/256, 256, 0, stream>>>(ei, CUR, CSRC);
  econv_kernel<<<8192, 64, 0, stream>>>(RPTR, CSRC, P, Q, c1b1, c1w2, c1b2, X);

  // dynamic layer 1
  sq_kernel<<<BNn*Hd/256, 256, 0, stream>>>(X, SQ);
  gemm_pq_kernel<64><<<BNn/8, 128, 0, stream>>>(X, WPQ1, P, Q);
  knn_kernel<<<Bg*(Ng/RT), 256, 0, stream>>>(X, SQ, IDX);
  dedge_kernel<true><<<8192, 64, 0, stream>>>(P, Q, IDX, d1b1, d1w2, d1b2, X);

  // dynamic layer 2
  sq_kernel<<<BNn*Hd/256, 256, 0, stream>>>(X, SQ);
  gemm_pq_kernel<64><<<BNn/8, 128, 0, stream>>>(X, WPQ2, P, Q);
  knn_kernel<<<Bg*(Ng/RT), 256, 0, stream>>>(X, SQ, IDX);
  dedge_kernel<false><<<8192, 64, 0, stream>>>(P, Q, IDX, d2b1, d2w2, d2b2, H2);

  final_kernel<<<8192, 64, 0, stream>>>(H2, linw, linb, out);
}